// Round 7
// baseline (363.799 us; speedup 1.0000x reference)
//
#include <hip/hip_runtime.h>
#include <hip/hip_bf16.h>
#include <cstdint>
#include <cstddef>

#define NN 50000
#define NE 800000
#define INC 128
#define HIDC 256
#define NH 4
#define OUTC 40

typedef __attribute__((ext_vector_type(8))) short short8_t;
typedef __attribute__((ext_vector_type(4))) float f32x4_t;

__device__ __forceinline__ float lrelu(float x){ return x > 0.f ? x : 0.2f*x; }
__device__ __forceinline__ unsigned short bfr(float f){
  __hip_bfloat16 h = __float2bfloat16(f);
  return *reinterpret_cast<unsigned short*>(&h);
}
__device__ __forceinline__ float bflo(unsigned u){ return __uint_as_float(u << 16); }
__device__ __forceinline__ float bfhi(unsigned u){ return __uint_as_float(u & 0xffff0000u); }

// ---- edge dtype detection: int64 view of int32 pairs gives values >= 2^32 ----
__global__ __launch_bounds__(64) void k_detect(const long long* __restrict__ ei, int* __restrict__ flag){
  int t = threadIdx.x;
  long long v = ei[(long long)t * (NE/64)];
  bool ok = (v >= 0) && (v < NN);
  unsigned long long m = __ballot(ok);
  if (t == 0) *flag = (m == 0xFFFFFFFFFFFFFFFFull) ? 1 : 0;
}

__global__ __launch_bounds__(256) void k_convert(const void* __restrict__ ei, const int* __restrict__ flag,
                                                 int* __restrict__ src32, int* __restrict__ dst32){
  int e = blockIdx.x*256 + threadIdx.x;
  if (e >= NE) return;
  int s, d;
  if (*flag){
    const long long* p = (const long long*)ei;
    s = (int)p[e]; d = (int)p[NE+e];
  } else {
    const int* p = (const int*)ei;
    s = p[e]; d = p[NE+e];
  }
  s = min(max(s,0),NN-1); d = min(max(d,0),NN-1);
  src32[e] = s; dst32[e] = d;
}

__global__ __launch_bounds__(256) void k_count(const int* __restrict__ dst32, int* __restrict__ deg){
  int e = blockIdx.x*256 + threadIdx.x;
  if (e < NE) atomicAdd(&deg[dst32[e]], 1);
}

// ---- exclusive scan of deg -> rowptr (3-kernel, chunk=1024) ----
__global__ __launch_bounds__(1024) void k_scan1(const int* __restrict__ deg, int* __restrict__ rowptr, int* __restrict__ sums){
  __shared__ int sh[1024];
  int t = threadIdx.x; int i = blockIdx.x*1024 + t;
  sh[t] = (i < NN) ? deg[i] : 0;
  __syncthreads();
  for (int off = 1; off < 1024; off <<= 1){
    int add = (t >= off) ? sh[t-off] : 0;
    __syncthreads();
    sh[t] += add;
    __syncthreads();
  }
  if (i < NN) rowptr[i+1] = sh[t];
  if (t == 1023) sums[blockIdx.x] = sh[1023];
}

__global__ void k_scan2(int* sums, int nchunks){
  if (threadIdx.x == 0 && blockIdx.x == 0){
    int acc = 0;
    for (int i = 0; i < nchunks; i++){ int v = sums[i]; sums[i] = acc; acc += v; }
  }
}

__global__ __launch_bounds__(256) void k_scan3(int* __restrict__ rowptr, const int* __restrict__ sums){
  int i = blockIdx.x*256 + threadIdx.x;
  if (i < NN) rowptr[i+1] += sums[i >> 10];
  if (i == 0) rowptr[0] = 0;
}

__global__ __launch_bounds__(256) void k_fill(const int* __restrict__ src32, const int* __restrict__ dst32,
                                              const int* __restrict__ rowptr, int* __restrict__ fill,
                                              int* __restrict__ colsrc, int* __restrict__ epos){
  int e = blockIdx.x*256 + threadIdx.x;
  if (e >= NE) return;
  int d = dst32[e];
  int pos = rowptr[d] + atomicAdd(&fill[d], 1);
  colsrc[pos] = src32[e];
  epos[e] = pos;
}

// ---- fp32 -> bf16 conversion (used for W1) ----
__global__ __launch_bounds__(256) void k_cvt(const float* __restrict__ in, unsigned short* __restrict__ out, int n4){
  int i = blockIdx.x*256 + threadIdx.x;
  if (i >= n4) return;
  float4 v = ((const float4*)in)[i];
  ushort4 o;
  o.x = bfr(v.x); o.y = bfr(v.y); o.z = bfr(v.z); o.w = bfr(v.w);
  ((ushort4*)out)[i] = o;
}

// ---- layer1 GEMM: MFMA bf16, wave = 16 rows x 256 cols, fused attention dots ----
__global__ __launch_bounds__(256) void k_gemm1(const float* __restrict__ x, const unsigned short* __restrict__ w1b,
    const float* __restrict__ atts, const float* __restrict__ attd,
    unsigned short* __restrict__ h1b, float* __restrict__ as1, float* __restrict__ ad1){
  int tid = threadIdx.x;
  int wv = tid >> 6, l = tid & 63;
  int m0 = blockIdx.x*64 + wv*16;
  int lr = l & 15;
  int lk = l >> 4;

  short8_t a[4];
  int arow = m0 + lr; if (arow > NN-1) arow = NN-1;
  const float* xrow = x + (size_t)arow*INC + lk*8;
  #pragma unroll
  for (int kt = 0; kt < 4; kt++){
    float4 f0 = *(const float4*)(xrow + kt*32);
    float4 f1 = *(const float4*)(xrow + kt*32 + 4);
    short8_t av;
    av[0] = (short)bfr(f0.x); av[1] = (short)bfr(f0.y);
    av[2] = (short)bfr(f0.z); av[3] = (short)bfr(f0.w);
    av[4] = (short)bfr(f1.x); av[5] = (short)bfr(f1.y);
    av[6] = (short)bfr(f1.z); av[7] = (short)bfr(f1.w);
    a[kt] = av;
  }

  const unsigned short* bbase = w1b + (size_t)lr*INC + lk*8;

  for (int h = 0; h < NH; h++){
    float ps[4] = {0.f,0.f,0.f,0.f};
    float pd[4] = {0.f,0.f,0.f,0.f};
    #pragma unroll
    for (int t = 0; t < 4; t++){
      int nt = h*4 + t;
      f32x4_t acc = {0.f,0.f,0.f,0.f};
      #pragma unroll
      for (int kt = 0; kt < 4; kt++){
        short8_t bv = *(const short8_t*)(bbase + (size_t)nt*16*INC + kt*32);
        acc = __builtin_amdgcn_mfma_f32_16x16x32_bf16(a[kt], bv, acc, 0, 0, 0);
      }
      float sa = atts[nt*16 + lr], sd = attd[nt*16 + lr];
      #pragma unroll
      for (int r = 0; r < 4; r++){
        float v = acc[r];
        ps[r] += v*sa; pd[r] += v*sd;
        int node = m0 + lk*4 + r;
        if (node < NN) h1b[(size_t)node*HIDC + nt*16 + lr] = bfr(v);
      }
    }
    #pragma unroll
    for (int r = 0; r < 4; r++){
      float p = ps[r], q = pd[r];
      p += __shfl_xor(p, 1); p += __shfl_xor(p, 2); p += __shfl_xor(p, 4); p += __shfl_xor(p, 8);
      q += __shfl_xor(q, 1); q += __shfl_xor(q, 2); q += __shfl_xor(q, 4); q += __shfl_xor(q, 8);
      int node = m0 + lk*4 + r;
      if (lr == 0 && node < NN){ as1[node*NH + h] = p; ad1[node*NH + h] = q; }
    }
  }
}

// ---- per-edge attention weights, planar layout esp[head][pos] ----
__global__ __launch_bounds__(256) void k_es(const int* __restrict__ src32, const int* __restrict__ dst32,
    const int* __restrict__ epos, const float* __restrict__ as1, const float* __restrict__ ad1,
    float* __restrict__ esp){
  int e = blockIdx.x*256 + threadIdx.x;
  if (e >= NE) return;
  int s = src32[e], d = dst32[e];
  float4 vs = ((const float4*)as1)[s];
  float4 vd = ((const float4*)ad1)[d];
  int pos = epos[e];
  esp[0*NE + pos] = __expf(lrelu(vs.x + vd.x));
  esp[1*NE + pos] = __expf(lrelu(vs.y + vd.y));
  esp[2*NE + pos] = __expf(lrelu(vs.z + vd.z));
  esp[3*NE + pos] = __expf(lrelu(vs.w + vd.w));
}

// ---- layer1 aggregation v2: 1 wave/node, 4 ch/thread (uint2 gather = full 512B row/wave),
//      planar es (1 dword/edge/lane), unroll-4 MLP, bf16 h1a output ----
__global__ __launch_bounds__(64) void k_agg1(const unsigned short* __restrict__ h1b,
    const float* __restrict__ esp, const float* __restrict__ as1, const float* __restrict__ ad1,
    const int* __restrict__ rowptr, const int* __restrict__ colsrc,
    const float* __restrict__ b1, unsigned short* __restrict__ h1a){
  int n = blockIdx.x; int tid = threadIdx.x; int head = tid >> 4;
  const uint2* h1q = (const uint2*)h1b;          // row = 64 uint2
  const float* esh = esp + (size_t)head*NE;

  float es_self = __expf(lrelu(as1[n*NH + head] + ad1[n*NH + head]));
  float den = 1e-16f + es_self;
  uint2 v = h1q[(size_t)n*64 + tid];
  float a0 = es_self * bflo(v.x);
  float a1 = es_self * bfhi(v.x);
  float a2 = es_self * bflo(v.y);
  float a3 = es_self * bfhi(v.y);

  int beg = rowptr[n], end = rowptr[n+1];
  int j = beg;
  for (; j + 3 < end; j += 4){
    int s0 = colsrc[j], s1 = colsrc[j+1], s2 = colsrc[j+2], s3 = colsrc[j+3];
    float w0 = esh[j], w1 = esh[j+1], w2 = esh[j+2], w3 = esh[j+3];
    uint2 v0 = h1q[(size_t)s0*64 + tid];
    uint2 v1 = h1q[(size_t)s1*64 + tid];
    uint2 v2 = h1q[(size_t)s2*64 + tid];
    uint2 v3 = h1q[(size_t)s3*64 + tid];
    den += (w0 + w1) + (w2 + w3);
    a0 += w0*bflo(v0.x); a1 += w0*bfhi(v0.x); a2 += w0*bflo(v0.y); a3 += w0*bfhi(v0.y);
    a0 += w1*bflo(v1.x); a1 += w1*bfhi(v1.x); a2 += w1*bflo(v1.y); a3 += w1*bfhi(v1.y);
    a0 += w2*bflo(v2.x); a1 += w2*bfhi(v2.x); a2 += w2*bflo(v2.y); a3 += w2*bfhi(v2.y);
    a0 += w3*bflo(v3.x); a1 += w3*bfhi(v3.x); a2 += w3*bflo(v3.y); a3 += w3*bfhi(v3.y);
  }
  for (; j < end; j++){
    int s0 = colsrc[j];
    float w0 = esh[j];
    uint2 v0 = h1q[(size_t)s0*64 + tid];
    den += w0;
    a0 += w0*bflo(v0.x); a1 += w0*bfhi(v0.x); a2 += w0*bflo(v0.y); a3 += w0*bfhi(v0.y);
  }

  float4 bb = ((const float4*)b1)[tid];
  float rinv = 1.f / den;
  float o0 = a0*rinv + bb.x;
  float o1 = a1*rinv + bb.y;
  float o2 = a2*rinv + bb.z;
  float o3 = a3*rinv + bb.w;
  o0 = o0 > 0.f ? o0 : (__expf(o0) - 1.f);
  o1 = o1 > 0.f ? o1 : (__expf(o1) - 1.f);
  o2 = o2 > 0.f ? o2 : (__expf(o2) - 1.f);
  o3 = o3 > 0.f ? o3 : (__expf(o3) - 1.f);
  uint2 pkd;
  pkd.x = (unsigned)bfr(o0) | ((unsigned)bfr(o1) << 16);
  pkd.y = (unsigned)bfr(o2) | ((unsigned)bfr(o3) << 16);
  ((uint2*)h1a)[(size_t)n*64 + tid] = pkd;
}

// ---- layer2 GEMM: one node per thread, W2^T staged in LDS, bf16 h1a input ----
__global__ __launch_bounds__(256) void k_gemm2(const unsigned short* __restrict__ h1a, const float* __restrict__ W2,
    const float* __restrict__ atts2, const float* __restrict__ attd2,
    float* __restrict__ h2, float* __restrict__ a2s, float* __restrict__ a2d){
  __shared__ float W2t[HIDC*OUTC];   // [k][c] transposed, 40 KB
  __shared__ float sA[OUTC], sD[OUTC];
  int tid = threadIdx.x;
  #pragma unroll
  for (int it = 0; it < (OUTC*HIDC)/256; it++){
    int idx = it*256 + tid;
    int c = idx >> 8, k = idx & 255;
    W2t[k*OUTC + c] = W2[idx];
  }
  if (tid < OUTC){ sA[tid] = atts2[tid]; sD[tid] = attd2[tid]; }
  __syncthreads();

  int n = blockIdx.x*256 + tid;
  if (n >= NN) return;

  float acc[OUTC];
  #pragma unroll
  for (int c = 0; c < OUTC; c++) acc[c] = 0.f;

  const uint2* x2p = (const uint2*)(h1a + (size_t)n*HIDC);
  const float4* w4p = (const float4*)W2t;
  #pragma unroll 2
  for (int k4 = 0; k4 < HIDC/4; k4++){
    uint2 xu = x2p[k4];
    float xk[4] = { bflo(xu.x), bfhi(xu.x), bflo(xu.y), bfhi(xu.y) };
    #pragma unroll
    for (int kk = 0; kk < 4; kk++){
      #pragma unroll
      for (int c4 = 0; c4 < OUTC/4; c4++){
        float4 wv = w4p[(k4*4 + kk)*(OUTC/4) + c4];
        acc[c4*4+0] += xk[kk]*wv.x;
        acc[c4*4+1] += xk[kk]*wv.y;
        acc[c4*4+2] += xk[kk]*wv.z;
        acc[c4*4+3] += xk[kk]*wv.w;
      }
    }
  }

  float s2 = 0.f, d2 = 0.f;
  #pragma unroll
  for (int c = 0; c < OUTC; c++){ s2 += acc[c]*sA[c]; d2 += acc[c]*sD[c]; }

  float* h2row = h2 + (size_t)n*OUTC;
  #pragma unroll
  for (int c4 = 0; c4 < OUTC/4; c4++){
    float4 v; v.x = acc[c4*4+0]; v.y = acc[c4*4+1]; v.z = acc[c4*4+2]; v.w = acc[c4*4+3];
    ((float4*)h2row)[c4] = v;
  }
  a2s[n] = s2; a2d[n] = d2;
}

// ---- layer2 aggregation: softmax-weighted mean + bias -> out ----
__global__ __launch_bounds__(64) void k_agg2(const float* __restrict__ h2, const float* __restrict__ a2s,
    const float* __restrict__ a2d, const int* __restrict__ rowptr, const int* __restrict__ colsrc,
    const float* __restrict__ b2, float* __restrict__ out){
  int n = blockIdx.x; int tid = threadIdx.x;
  float adn = a2d[n];
  float e = __expf(lrelu(a2s[n] + adn));
  float den = 1e-16f + e;
  float acc = (tid < OUTC) ? e * h2[(size_t)n*OUTC + tid] : 0.f;
  int beg = rowptr[n], end = rowptr[n+1];
  for (int j = beg; j < end; j++){
    int s = colsrc[j];
    float es = __expf(lrelu(a2s[s] + adn));
    if (tid < OUTC) acc += es * h2[(size_t)s*OUTC + tid];
    den += es;
  }
  if (tid < OUTC) out[(size_t)n*OUTC + tid] = acc/den + b2[tid];
}

extern "C" void kernel_launch(void* const* d_in, const int* in_sizes, int n_in,
                              void* d_out, int out_size, void* d_ws, size_t ws_size,
                              hipStream_t stream){
  const float* x    = (const float*)d_in[0];
  const void*  ei   = d_in[1];
  const float* W1   = (const float*)d_in[2];
  const float* as1w = (const float*)d_in[3];
  const float* ad1w = (const float*)d_in[4];
  const float* b1   = (const float*)d_in[5];
  const float* W2   = (const float*)d_in[6];
  const float* as2w = (const float*)d_in[7];
  const float* ad2w = (const float*)d_in[8];
  const float* b2   = (const float*)d_in[9];
  float* out = (float*)d_out;

  char* base = (char*)d_ws;
  size_t off = 0;
  auto alloc = [&](size_t bytes)->char*{ char* r = base + off; off += (bytes + 255) & ~(size_t)255; return r; };
  int* flag   = (int*)alloc(sizeof(int));
  int* src32  = (int*)alloc((size_t)NE*sizeof(int));
  int* dst32  = (int*)alloc((size_t)NE*sizeof(int));
  int* deg    = (int*)alloc((size_t)NN*sizeof(int));
  int* rowptr = (int*)alloc((size_t)(NN+1)*sizeof(int));
  int* fillc  = (int*)alloc((size_t)NN*sizeof(int));
  int* sums   = (int*)alloc(64*sizeof(int));
  int* colsrc = (int*)alloc((size_t)NE*sizeof(int));
  int* epos   = (int*)alloc((size_t)NE*sizeof(int));
  float* esp  = (float*)alloc((size_t)NE*NH*sizeof(float));
  unsigned short* w1b = (unsigned short*)alloc((size_t)HIDC*INC*sizeof(unsigned short));
  unsigned short* h1b = (unsigned short*)alloc((size_t)NN*HIDC*sizeof(unsigned short));
  unsigned short* h1a = (unsigned short*)alloc((size_t)NN*HIDC*sizeof(unsigned short));
  float* as1  = (float*)alloc((size_t)NN*NH*sizeof(float));
  float* ad1  = (float*)alloc((size_t)NN*NH*sizeof(float));
  float* h2   = (float*)alloc((size_t)NN*OUTC*sizeof(float));
  float* a2s  = (float*)alloc((size_t)NN*sizeof(float));
  float* a2d  = (float*)alloc((size_t)NN*sizeof(float));

  hipMemsetAsync(deg,   0, (size_t)NN*sizeof(int), stream);
  hipMemsetAsync(fillc, 0, (size_t)NN*sizeof(int), stream);

  int gE = (NE + 255)/256;
  int nchunks = (NN + 1023)/1024;
  k_detect<<<1, 64, 0, stream>>>((const long long*)ei, flag);
  k_convert<<<gE, 256, 0, stream>>>(ei, flag, src32, dst32);
  k_count<<<gE, 256, 0, stream>>>(dst32, deg);
  k_scan1<<<nchunks, 1024, 0, stream>>>(deg, rowptr, sums);
  k_scan2<<<1, 64, 0, stream>>>(sums, nchunks);
  k_scan3<<<(NN + 255)/256, 256, 0, stream>>>(rowptr, sums);
  k_fill<<<gE, 256, 0, stream>>>(src32, dst32, rowptr, fillc, colsrc, epos);
  k_cvt<<<(HIDC*INC/4 + 255)/256, 256, 0, stream>>>(W1, w1b, HIDC*INC/4);
  k_gemm1<<<(NN + 63)/64, 256, 0, stream>>>(x, w1b, as1w, ad1w, h1b, as1, ad1);
  k_es<<<gE, 256, 0, stream>>>(src32, dst32, epos, as1, ad1, esp);
  k_agg1<<<NN, 64, 0, stream>>>(h1b, esp, as1, ad1, rowptr, colsrc, b1, h1a);
  k_gemm2<<<(NN + 255)/256, 256, 0, stream>>>(h1a, W2, as2w, ad2w, h2, a2s, a2d);
  k_agg2<<<NN, 64, 0, stream>>>(h2, a2s, a2d, rowptr, colsrc, b2, out);
}

// Round 8
// 333.872 us; speedup vs baseline: 1.0896x; 1.0896x over previous
//
#include <hip/hip_runtime.h>
#include <hip/hip_bf16.h>
#include <cstdint>
#include <cstddef>

#define NN 50000
#define NE 800000
#define INC 128
#define HIDC 256
#define NH 4
#define OUTC 40

typedef __attribute__((ext_vector_type(8))) short short8_t;
typedef __attribute__((ext_vector_type(4))) float f32x4_t;

__device__ __forceinline__ float lrelu(float x){ return x > 0.f ? x : 0.2f*x; }
__device__ __forceinline__ unsigned short bfr(float f){
  __hip_bfloat16 h = __float2bfloat16(f);
  return *reinterpret_cast<unsigned short*>(&h);
}
__device__ __forceinline__ float bflo(unsigned u){ return __uint_as_float(u << 16); }
__device__ __forceinline__ float bfhi(unsigned u){ return __uint_as_float(u & 0xffff0000u); }

// ---- edge dtype detection: int64 view of int32 pairs gives values >= 2^32 ----
__global__ __launch_bounds__(64) void k_detect(const long long* __restrict__ ei, int* __restrict__ flag){
  int t = threadIdx.x;
  long long v = ei[(long long)t * (NE/64)];
  bool ok = (v >= 0) && (v < NN);
  unsigned long long m = __ballot(ok);
  if (t == 0) *flag = (m == 0xFFFFFFFFFFFFFFFFull) ? 1 : 0;
}

__global__ __launch_bounds__(256) void k_convert(const void* __restrict__ ei, const int* __restrict__ flag,
                                                 int* __restrict__ src32, int* __restrict__ dst32){
  int e = blockIdx.x*256 + threadIdx.x;
  if (e >= NE) return;
  int s, d;
  if (*flag){
    const long long* p = (const long long*)ei;
    s = (int)p[e]; d = (int)p[NE+e];
  } else {
    const int* p = (const int*)ei;
    s = p[e]; d = p[NE+e];
  }
  s = min(max(s,0),NN-1); d = min(max(d,0),NN-1);
  src32[e] = s; dst32[e] = d;
}

__global__ __launch_bounds__(256) void k_count(const int* __restrict__ dst32, int* __restrict__ deg){
  int e = blockIdx.x*256 + threadIdx.x;
  if (e < NE) atomicAdd(&deg[dst32[e]], 1);
}

// ---- exclusive scan of deg -> rowptr (3-kernel, chunk=1024) ----
__global__ __launch_bounds__(1024) void k_scan1(const int* __restrict__ deg, int* __restrict__ rowptr, int* __restrict__ sums){
  __shared__ int sh[1024];
  int t = threadIdx.x; int i = blockIdx.x*1024 + t;
  sh[t] = (i < NN) ? deg[i] : 0;
  __syncthreads();
  for (int off = 1; off < 1024; off <<= 1){
    int add = (t >= off) ? sh[t-off] : 0;
    __syncthreads();
    sh[t] += add;
    __syncthreads();
  }
  if (i < NN) rowptr[i+1] = sh[t];
  if (t == 1023) sums[blockIdx.x] = sh[1023];
}

__global__ void k_scan2(int* sums, int nchunks){
  if (threadIdx.x == 0 && blockIdx.x == 0){
    int acc = 0;
    for (int i = 0; i < nchunks; i++){ int v = sums[i]; sums[i] = acc; acc += v; }
  }
}

__global__ __launch_bounds__(256) void k_scan3(int* __restrict__ rowptr, const int* __restrict__ sums){
  int i = blockIdx.x*256 + threadIdx.x;
  if (i < NN) rowptr[i+1] += sums[i >> 10];
  if (i == 0) rowptr[0] = 0;
}

__global__ __launch_bounds__(256) void k_fill(const int* __restrict__ src32, const int* __restrict__ dst32,
                                              const int* __restrict__ rowptr, int* __restrict__ fill,
                                              int* __restrict__ colsrc, int* __restrict__ epos){
  int e = blockIdx.x*256 + threadIdx.x;
  if (e >= NE) return;
  int d = dst32[e];
  int pos = rowptr[d] + atomicAdd(&fill[d], 1);
  colsrc[pos] = src32[e];
  epos[e] = pos;
}

// ---- fp32 -> bf16 conversion (used for W1) ----
__global__ __launch_bounds__(256) void k_cvt(const float* __restrict__ in, unsigned short* __restrict__ out, int n4){
  int i = blockIdx.x*256 + threadIdx.x;
  if (i >= n4) return;
  float4 v = ((const float4*)in)[i];
  ushort4 o;
  o.x = bfr(v.x); o.y = bfr(v.y); o.z = bfr(v.z); o.w = bfr(v.w);
  ((ushort4*)out)[i] = o;
}

// ---- layer1 GEMM: MFMA bf16, wave = 16 rows x 256 cols, fused attention dots ----
__global__ __launch_bounds__(256) void k_gemm1(const float* __restrict__ x, const unsigned short* __restrict__ w1b,
    const float* __restrict__ atts, const float* __restrict__ attd,
    unsigned short* __restrict__ h1b, float* __restrict__ as1, float* __restrict__ ad1){
  int tid = threadIdx.x;
  int wv = tid >> 6, l = tid & 63;
  int m0 = blockIdx.x*64 + wv*16;
  int lr = l & 15;
  int lk = l >> 4;

  short8_t a[4];
  int arow = m0 + lr; if (arow > NN-1) arow = NN-1;
  const float* xrow = x + (size_t)arow*INC + lk*8;
  #pragma unroll
  for (int kt = 0; kt < 4; kt++){
    float4 f0 = *(const float4*)(xrow + kt*32);
    float4 f1 = *(const float4*)(xrow + kt*32 + 4);
    short8_t av;
    av[0] = (short)bfr(f0.x); av[1] = (short)bfr(f0.y);
    av[2] = (short)bfr(f0.z); av[3] = (short)bfr(f0.w);
    av[4] = (short)bfr(f1.x); av[5] = (short)bfr(f1.y);
    av[6] = (short)bfr(f1.z); av[7] = (short)bfr(f1.w);
    a[kt] = av;
  }

  const unsigned short* bbase = w1b + (size_t)lr*INC + lk*8;

  for (int h = 0; h < NH; h++){
    float ps[4] = {0.f,0.f,0.f,0.f};
    float pd[4] = {0.f,0.f,0.f,0.f};
    #pragma unroll
    for (int t = 0; t < 4; t++){
      int nt = h*4 + t;
      f32x4_t acc = {0.f,0.f,0.f,0.f};
      #pragma unroll
      for (int kt = 0; kt < 4; kt++){
        short8_t bv = *(const short8_t*)(bbase + (size_t)nt*16*INC + kt*32);
        acc = __builtin_amdgcn_mfma_f32_16x16x32_bf16(a[kt], bv, acc, 0, 0, 0);
      }
      float sa = atts[nt*16 + lr], sd = attd[nt*16 + lr];
      #pragma unroll
      for (int r = 0; r < 4; r++){
        float v = acc[r];
        ps[r] += v*sa; pd[r] += v*sd;
        int node = m0 + lk*4 + r;
        if (node < NN) h1b[(size_t)node*HIDC + nt*16 + lr] = bfr(v);
      }
    }
    #pragma unroll
    for (int r = 0; r < 4; r++){
      float p = ps[r], q = pd[r];
      p += __shfl_xor(p, 1); p += __shfl_xor(p, 2); p += __shfl_xor(p, 4); p += __shfl_xor(p, 8);
      q += __shfl_xor(q, 1); q += __shfl_xor(q, 2); q += __shfl_xor(q, 4); q += __shfl_xor(q, 8);
      int node = m0 + lk*4 + r;
      if (lr == 0 && node < NN){ as1[node*NH + h] = p; ad1[node*NH + h] = q; }
    }
  }
}

// ---- per-edge attention weights, planar layout esp[head][pos] ----
__global__ __launch_bounds__(256) void k_es(const int* __restrict__ src32, const int* __restrict__ dst32,
    const int* __restrict__ epos, const float* __restrict__ as1, const float* __restrict__ ad1,
    float* __restrict__ esp){
  int e = blockIdx.x*256 + threadIdx.x;
  if (e >= NE) return;
  int s = src32[e], d = dst32[e];
  float4 vs = ((const float4*)as1)[s];
  float4 vd = ((const float4*)ad1)[d];
  int pos = epos[e];
  esp[0*NE + pos] = __expf(lrelu(vs.x + vd.x));
  esp[1*NE + pos] = __expf(lrelu(vs.y + vd.y));
  esp[2*NE + pos] = __expf(lrelu(vs.z + vd.z));
  esp[3*NE + pos] = __expf(lrelu(vs.w + vd.w));
}

// ---- layer1 aggregation: 1 wave/node, 4 ch/thread, planar es, unroll-4, bf16 out ----
__global__ __launch_bounds__(64) void k_agg1(const unsigned short* __restrict__ h1b,
    const float* __restrict__ esp, const float* __restrict__ as1, const float* __restrict__ ad1,
    const int* __restrict__ rowptr, const int* __restrict__ colsrc,
    const float* __restrict__ b1, unsigned short* __restrict__ h1a){
  int n = blockIdx.x; int tid = threadIdx.x; int head = tid >> 4;
  const uint2* h1q = (const uint2*)h1b;          // row = 64 uint2
  const float* esh = esp + (size_t)head*NE;

  float es_self = __expf(lrelu(as1[n*NH + head] + ad1[n*NH + head]));
  float den = 1e-16f + es_self;
  uint2 v = h1q[(size_t)n*64 + tid];
  float a0 = es_self * bflo(v.x);
  float a1 = es_self * bfhi(v.x);
  float a2 = es_self * bflo(v.y);
  float a3 = es_self * bfhi(v.y);

  int beg = rowptr[n], end = rowptr[n+1];
  int j = beg;
  for (; j + 3 < end; j += 4){
    int s0 = colsrc[j], s1 = colsrc[j+1], s2 = colsrc[j+2], s3 = colsrc[j+3];
    float w0 = esh[j], w1 = esh[j+1], w2 = esh[j+2], w3 = esh[j+3];
    uint2 v0 = h1q[(size_t)s0*64 + tid];
    uint2 v1 = h1q[(size_t)s1*64 + tid];
    uint2 v2 = h1q[(size_t)s2*64 + tid];
    uint2 v3 = h1q[(size_t)s3*64 + tid];
    den += (w0 + w1) + (w2 + w3);
    a0 += w0*bflo(v0.x); a1 += w0*bfhi(v0.x); a2 += w0*bflo(v0.y); a3 += w0*bfhi(v0.y);
    a0 += w1*bflo(v1.x); a1 += w1*bfhi(v1.x); a2 += w1*bflo(v1.y); a3 += w1*bfhi(v1.y);
    a0 += w2*bflo(v2.x); a1 += w2*bfhi(v2.x); a2 += w2*bflo(v2.y); a3 += w2*bfhi(v2.y);
    a0 += w3*bflo(v3.x); a1 += w3*bfhi(v3.x); a2 += w3*bflo(v3.y); a3 += w3*bfhi(v3.y);
  }
  for (; j < end; j++){
    int s0 = colsrc[j];
    float w0 = esh[j];
    uint2 v0 = h1q[(size_t)s0*64 + tid];
    den += w0;
    a0 += w0*bflo(v0.x); a1 += w0*bfhi(v0.x); a2 += w0*bflo(v0.y); a3 += w0*bfhi(v0.y);
  }

  float4 bb = ((const float4*)b1)[tid];
  float rinv = 1.f / den;
  float o0 = a0*rinv + bb.x;
  float o1 = a1*rinv + bb.y;
  float o2 = a2*rinv + bb.z;
  float o3 = a3*rinv + bb.w;
  o0 = o0 > 0.f ? o0 : (__expf(o0) - 1.f);
  o1 = o1 > 0.f ? o1 : (__expf(o1) - 1.f);
  o2 = o2 > 0.f ? o2 : (__expf(o2) - 1.f);
  o3 = o3 > 0.f ? o3 : (__expf(o3) - 1.f);
  uint2 pkd;
  pkd.x = (unsigned)bfr(o0) | ((unsigned)bfr(o1) << 16);
  pkd.y = (unsigned)bfr(o2) | ((unsigned)bfr(o3) << 16);
  ((uint2*)h1a)[(size_t)n*64 + tid] = pkd;
}

// ---- layer2 GEMM: one node per thread, W2^T staged in LDS, bf16 h1a input ----
__global__ __launch_bounds__(256) void k_gemm2(const unsigned short* __restrict__ h1a, const float* __restrict__ W2,
    const float* __restrict__ atts2, const float* __restrict__ attd2,
    float* __restrict__ h2, float* __restrict__ a2s, float* __restrict__ a2d){
  __shared__ float W2t[HIDC*OUTC];   // [k][c] transposed, 40 KB
  __shared__ float sA[OUTC], sD[OUTC];
  int tid = threadIdx.x;
  #pragma unroll
  for (int it = 0; it < (OUTC*HIDC)/256; it++){
    int idx = it*256 + tid;
    int c = idx >> 8, k = idx & 255;
    W2t[k*OUTC + c] = W2[idx];
  }
  if (tid < OUTC){ sA[tid] = atts2[tid]; sD[tid] = attd2[tid]; }
  __syncthreads();

  int n = blockIdx.x*256 + tid;
  if (n >= NN) return;

  float acc[OUTC];
  #pragma unroll
  for (int c = 0; c < OUTC; c++) acc[c] = 0.f;

  const uint2* x2p = (const uint2*)(h1a + (size_t)n*HIDC);
  const float4* w4p = (const float4*)W2t;
  #pragma unroll 2
  for (int k4 = 0; k4 < HIDC/4; k4++){
    uint2 xu = x2p[k4];
    float xk[4] = { bflo(xu.x), bfhi(xu.x), bflo(xu.y), bfhi(xu.y) };
    #pragma unroll
    for (int kk = 0; kk < 4; kk++){
      #pragma unroll
      for (int c4 = 0; c4 < OUTC/4; c4++){
        float4 wv = w4p[(k4*4 + kk)*(OUTC/4) + c4];
        acc[c4*4+0] += xk[kk]*wv.x;
        acc[c4*4+1] += xk[kk]*wv.y;
        acc[c4*4+2] += xk[kk]*wv.z;
        acc[c4*4+3] += xk[kk]*wv.w;
      }
    }
  }

  float s2 = 0.f, d2 = 0.f;
  #pragma unroll
  for (int c = 0; c < OUTC; c++){ s2 += acc[c]*sA[c]; d2 += acc[c]*sD[c]; }

  float* h2row = h2 + (size_t)n*OUTC;
  #pragma unroll
  for (int c4 = 0; c4 < OUTC/4; c4++){
    float4 v; v.x = acc[c4*4+0]; v.y = acc[c4*4+1]; v.z = acc[c4*4+2]; v.w = acc[c4*4+3];
    ((float4*)h2row)[c4] = v;
  }
  a2s[n] = s2; a2d[n] = d2;
}

// ---- per-edge layer2 attention weights: es2[pos] = exp(lrelu(a2s[s]+a2d[d])) ----
__global__ __launch_bounds__(256) void k_es2(const int* __restrict__ src32, const int* __restrict__ dst32,
    const int* __restrict__ epos, const float* __restrict__ a2s, const float* __restrict__ a2d,
    float* __restrict__ es2){
  int e = blockIdx.x*256 + threadIdx.x;
  if (e >= NE) return;
  es2[epos[e]] = __expf(lrelu(a2s[src32[e]] + a2d[dst32[e]]));
}

// ---- layer2 aggregation v2: precomputed es2, unroll-4 gathers, no exp in chain ----
__global__ __launch_bounds__(64) void k_agg2(const float* __restrict__ h2, const float* __restrict__ a2s,
    const float* __restrict__ a2d, const float* __restrict__ es2,
    const int* __restrict__ rowptr, const int* __restrict__ colsrc,
    const float* __restrict__ b2, float* __restrict__ out){
  int n = blockIdx.x; int tid = threadIdx.x;
  int c = tid < OUTC ? tid : OUTC-1;          // clamp: no divergence, valid addrs
  float e = __expf(lrelu(a2s[n] + a2d[n]));
  float den = 1e-16f + e;
  float acc = e * h2[(size_t)n*OUTC + c];
  int beg = rowptr[n], end = rowptr[n+1];
  int j = beg;
  for (; j + 3 < end; j += 4){
    int s0 = colsrc[j], s1 = colsrc[j+1], s2 = colsrc[j+2], s3 = colsrc[j+3];
    float w0 = es2[j], w1 = es2[j+1], w2 = es2[j+2], w3 = es2[j+3];
    float g0 = h2[(size_t)s0*OUTC + c];
    float g1 = h2[(size_t)s1*OUTC + c];
    float g2 = h2[(size_t)s2*OUTC + c];
    float g3 = h2[(size_t)s3*OUTC + c];
    den += (w0 + w1) + (w2 + w3);
    acc += w0*g0 + w1*g1;
    acc += w2*g2 + w3*g3;
  }
  for (; j < end; j++){
    int s0 = colsrc[j];
    float w0 = es2[j];
    acc += w0 * h2[(size_t)s0*OUTC + c];
    den += w0;
  }
  if (tid < OUTC) out[(size_t)n*OUTC + tid] = acc/den + b2[tid];
}

extern "C" void kernel_launch(void* const* d_in, const int* in_sizes, int n_in,
                              void* d_out, int out_size, void* d_ws, size_t ws_size,
                              hipStream_t stream){
  const float* x    = (const float*)d_in[0];
  const void*  ei   = d_in[1];
  const float* W1   = (const float*)d_in[2];
  const float* as1w = (const float*)d_in[3];
  const float* ad1w = (const float*)d_in[4];
  const float* b1   = (const float*)d_in[5];
  const float* W2   = (const float*)d_in[6];
  const float* as2w = (const float*)d_in[7];
  const float* ad2w = (const float*)d_in[8];
  const float* b2   = (const float*)d_in[9];
  float* out = (float*)d_out;

  char* base = (char*)d_ws;
  size_t off = 0;
  auto alloc = [&](size_t bytes)->char*{ char* r = base + off; off += (bytes + 255) & ~(size_t)255; return r; };
  int* flag   = (int*)alloc(sizeof(int));
  int* src32  = (int*)alloc((size_t)NE*sizeof(int));
  int* dst32  = (int*)alloc((size_t)NE*sizeof(int));
  int* deg    = (int*)alloc((size_t)NN*sizeof(int));
  int* rowptr = (int*)alloc((size_t)(NN+1)*sizeof(int));
  int* fillc  = (int*)alloc((size_t)NN*sizeof(int));
  int* sums   = (int*)alloc(64*sizeof(int));
  int* colsrc = (int*)alloc((size_t)NE*sizeof(int));
  int* epos   = (int*)alloc((size_t)NE*sizeof(int));
  float* esp  = (float*)alloc((size_t)NE*NH*sizeof(float));
  float* es2  = (float*)alloc((size_t)NE*sizeof(float));
  unsigned short* w1b = (unsigned short*)alloc((size_t)HIDC*INC*sizeof(unsigned short));
  unsigned short* h1b = (unsigned short*)alloc((size_t)NN*HIDC*sizeof(unsigned short));
  unsigned short* h1a = (unsigned short*)alloc((size_t)NN*HIDC*sizeof(unsigned short));
  float* as1  = (float*)alloc((size_t)NN*NH*sizeof(float));
  float* ad1  = (float*)alloc((size_t)NN*NH*sizeof(float));
  float* h2   = (float*)alloc((size_t)NN*OUTC*sizeof(float));
  float* a2s  = (float*)alloc((size_t)NN*sizeof(float));
  float* a2d  = (float*)alloc((size_t)NN*sizeof(float));

  hipMemsetAsync(deg,   0, (size_t)NN*sizeof(int), stream);
  hipMemsetAsync(fillc, 0, (size_t)NN*sizeof(int), stream);

  int gE = (NE + 255)/256;
  int nchunks = (NN + 1023)/1024;
  k_detect<<<1, 64, 0, stream>>>((const long long*)ei, flag);
  k_convert<<<gE, 256, 0, stream>>>(ei, flag, src32, dst32);
  k_count<<<gE, 256, 0, stream>>>(dst32, deg);
  k_scan1<<<nchunks, 1024, 0, stream>>>(deg, rowptr, sums);
  k_scan2<<<1, 64, 0, stream>>>(sums, nchunks);
  k_scan3<<<(NN + 255)/256, 256, 0, stream>>>(rowptr, sums);
  k_fill<<<gE, 256, 0, stream>>>(src32, dst32, rowptr, fillc, colsrc, epos);
  k_cvt<<<(HIDC*INC/4 + 255)/256, 256, 0, stream>>>(W1, w1b, HIDC*INC/4);
  k_gemm1<<<(NN + 63)/64, 256, 0, stream>>>(x, w1b, as1w, ad1w, h1b, as1, ad1);
  k_es<<<gE, 256, 0, stream>>>(src32, dst32, epos, as1, ad1, esp);
  k_agg1<<<NN, 64, 0, stream>>>(h1b, esp, as1, ad1, rowptr, colsrc, b1, h1a);
  k_gemm2<<<(NN + 255)/256, 256, 0, stream>>>(h1a, W2, as2w, ad2w, h2, a2s, a2d);
  k_es2<<<gE, 256, 0, stream>>>(src32, dst32, epos, a2s, a2d, es2);
  k_agg2<<<NN, 64, 0, stream>>>(h2, a2s, a2d, es2, rowptr, colsrc, b2, out);
}

// Round 9
// 302.592 us; speedup vs baseline: 1.2023x; 1.1034x over previous
//
#include <hip/hip_runtime.h>
#include <hip/hip_bf16.h>
#include <cstdint>
#include <cstddef>

#define NN 50000
#define NE 800000
#define INC 128
#define HIDC 256
#define NH 4
#define OUTC 40

typedef __attribute__((ext_vector_type(8))) short short8_t;
typedef __attribute__((ext_vector_type(4))) float f32x4_t;

__device__ __forceinline__ float lrelu(float x){ return x > 0.f ? x : 0.2f*x; }
__device__ __forceinline__ unsigned short bfr(float f){
  __hip_bfloat16 h = __float2bfloat16(f);
  return *reinterpret_cast<unsigned short*>(&h);
}
__device__ __forceinline__ float bflo(unsigned u){ return __uint_as_float(u << 16); }
__device__ __forceinline__ float bfhi(unsigned u){ return __uint_as_float(u & 0xffff0000u); }

// ---- edge dtype detection: int64 view of int32 pairs gives values >= 2^32 ----
__global__ __launch_bounds__(64) void k_detect(const long long* __restrict__ ei, int* __restrict__ flag){
  int t = threadIdx.x;
  long long v = ei[(long long)t * (NE/64)];
  bool ok = (v >= 0) && (v < NN);
  unsigned long long m = __ballot(ok);
  if (t == 0) *flag = (m == 0xFFFFFFFFFFFFFFFFull) ? 1 : 0;
}

// ---- convert + degree count fused ----
__global__ __launch_bounds__(256) void k_convert(const void* __restrict__ ei, const int* __restrict__ flag,
                                                 int* __restrict__ src32, int* __restrict__ dst32,
                                                 int* __restrict__ deg){
  int e = blockIdx.x*256 + threadIdx.x;
  if (e >= NE) return;
  int s, d;
  if (*flag){
    const long long* p = (const long long*)ei;
    s = (int)p[e]; d = (int)p[NE+e];
  } else {
    const int* p = (const int*)ei;
    s = p[e]; d = p[NE+e];
  }
  s = min(max(s,0),NN-1); d = min(max(d,0),NN-1);
  src32[e] = s; dst32[e] = d;
  atomicAdd(&deg[d], 1);
}

// ---- exclusive scan of deg -> rowptr (3-kernel, chunk=1024) ----
__global__ __launch_bounds__(1024) void k_scan1(const int* __restrict__ deg, int* __restrict__ rowptr, int* __restrict__ sums){
  __shared__ int sh[1024];
  int t = threadIdx.x; int i = blockIdx.x*1024 + t;
  sh[t] = (i < NN) ? deg[i] : 0;
  __syncthreads();
  for (int off = 1; off < 1024; off <<= 1){
    int add = (t >= off) ? sh[t-off] : 0;
    __syncthreads();
    sh[t] += add;
    __syncthreads();
  }
  if (i < NN) rowptr[i+1] = sh[t];
  if (t == 1023) sums[blockIdx.x] = sh[1023];
}

__global__ void k_scan2(int* sums, int nchunks){
  if (threadIdx.x == 0 && blockIdx.x == 0){
    int acc = 0;
    for (int i = 0; i < nchunks; i++){ int v = sums[i]; sums[i] = acc; acc += v; }
  }
}

__global__ __launch_bounds__(256) void k_scan3(int* __restrict__ rowptr, const int* __restrict__ sums){
  int i = blockIdx.x*256 + threadIdx.x;
  if (i < NN) rowptr[i+1] += sums[i >> 10];
  if (i == 0) rowptr[0] = 0;
}

// ---- CSR fill: colsrc + dstpos (no epos indirection) ----
__global__ __launch_bounds__(256) void k_fill(const int* __restrict__ src32, const int* __restrict__ dst32,
                                              const int* __restrict__ rowptr, int* __restrict__ fill,
                                              int* __restrict__ colsrc, int* __restrict__ dstpos){
  int e = blockIdx.x*256 + threadIdx.x;
  if (e >= NE) return;
  int d = dst32[e];
  int pos = rowptr[d] + atomicAdd(&fill[d], 1);
  colsrc[pos] = src32[e];
  dstpos[pos] = d;
}

// ---- fp32 -> bf16 conversion (used for W1) ----
__global__ __launch_bounds__(256) void k_cvt(const float* __restrict__ in, unsigned short* __restrict__ out, int n4){
  int i = blockIdx.x*256 + threadIdx.x;
  if (i >= n4) return;
  float4 v = ((const float4*)in)[i];
  ushort4 o;
  o.x = bfr(v.x); o.y = bfr(v.y); o.z = bfr(v.z); o.w = bfr(v.w);
  ((ushort4*)out)[i] = o;
}

// ---- layer1 GEMM: MFMA bf16, wave = 16 rows x 256 cols, fused attention dots ----
__global__ __launch_bounds__(256) void k_gemm1(const float* __restrict__ x, const unsigned short* __restrict__ w1b,
    const float* __restrict__ atts, const float* __restrict__ attd,
    unsigned short* __restrict__ h1b, float* __restrict__ as1, float* __restrict__ ad1){
  int tid = threadIdx.x;
  int wv = tid >> 6, l = tid & 63;
  int m0 = blockIdx.x*64 + wv*16;
  int lr = l & 15;
  int lk = l >> 4;

  short8_t a[4];
  int arow = m0 + lr; if (arow > NN-1) arow = NN-1;
  const float* xrow = x + (size_t)arow*INC + lk*8;
  #pragma unroll
  for (int kt = 0; kt < 4; kt++){
    float4 f0 = *(const float4*)(xrow + kt*32);
    float4 f1 = *(const float4*)(xrow + kt*32 + 4);
    short8_t av;
    av[0] = (short)bfr(f0.x); av[1] = (short)bfr(f0.y);
    av[2] = (short)bfr(f0.z); av[3] = (short)bfr(f0.w);
    av[4] = (short)bfr(f1.x); av[5] = (short)bfr(f1.y);
    av[6] = (short)bfr(f1.z); av[7] = (short)bfr(f1.w);
    a[kt] = av;
  }

  const unsigned short* bbase = w1b + (size_t)lr*INC + lk*8;

  for (int h = 0; h < NH; h++){
    float ps[4] = {0.f,0.f,0.f,0.f};
    float pd[4] = {0.f,0.f,0.f,0.f};
    #pragma unroll
    for (int t = 0; t < 4; t++){
      int nt = h*4 + t;
      f32x4_t acc = {0.f,0.f,0.f,0.f};
      #pragma unroll
      for (int kt = 0; kt < 4; kt++){
        short8_t bv = *(const short8_t*)(bbase + (size_t)nt*16*INC + kt*32);
        acc = __builtin_amdgcn_mfma_f32_16x16x32_bf16(a[kt], bv, acc, 0, 0, 0);
      }
      float sa = atts[nt*16 + lr], sd = attd[nt*16 + lr];
      #pragma unroll
      for (int r = 0; r < 4; r++){
        float v = acc[r];
        ps[r] += v*sa; pd[r] += v*sd;
        int node = m0 + lk*4 + r;
        if (node < NN) h1b[(size_t)node*HIDC + nt*16 + lr] = bfr(v);
      }
    }
    #pragma unroll
    for (int r = 0; r < 4; r++){
      float p = ps[r], q = pd[r];
      p += __shfl_xor(p, 1); p += __shfl_xor(p, 2); p += __shfl_xor(p, 4); p += __shfl_xor(p, 8);
      q += __shfl_xor(q, 1); q += __shfl_xor(q, 2); q += __shfl_xor(q, 4); q += __shfl_xor(q, 8);
      int node = m0 + lk*4 + r;
      if (lr == 0 && node < NN){ as1[node*NH + h] = p; ad1[node*NH + h] = q; }
    }
  }
}

// ---- per-edge attention weights, CSR order: coalesced colsrc/dstpos reads, coalesced planar writes ----
__global__ __launch_bounds__(256) void k_es(const int* __restrict__ colsrc, const int* __restrict__ dstpos,
    const float* __restrict__ as1, const float* __restrict__ ad1, float* __restrict__ esp){
  int pos = blockIdx.x*256 + threadIdx.x;
  if (pos >= NE) return;
  int s = colsrc[pos], d = dstpos[pos];
  float4 vs = ((const float4*)as1)[s];
  float4 vd = ((const float4*)ad1)[d];
  esp[0*NE + pos] = __expf(lrelu(vs.x + vd.x));
  esp[1*NE + pos] = __expf(lrelu(vs.y + vd.y));
  esp[2*NE + pos] = __expf(lrelu(vs.z + vd.z));
  esp[3*NE + pos] = __expf(lrelu(vs.w + vd.w));
}

// ---- layer1 aggregation: 1 wave/node, 4 ch/thread, planar es, unroll-4, bf16 out ----
__global__ __launch_bounds__(64) void k_agg1(const unsigned short* __restrict__ h1b,
    const float* __restrict__ esp, const float* __restrict__ as1, const float* __restrict__ ad1,
    const int* __restrict__ rowptr, const int* __restrict__ colsrc,
    const float* __restrict__ b1, unsigned short* __restrict__ h1a){
  int n = blockIdx.x; int tid = threadIdx.x; int head = tid >> 4;
  const uint2* h1q = (const uint2*)h1b;          // row = 64 uint2
  const float* esh = esp + (size_t)head*NE;

  float es_self = __expf(lrelu(as1[n*NH + head] + ad1[n*NH + head]));
  float den = 1e-16f + es_self;
  uint2 v = h1q[(size_t)n*64 + tid];
  float a0 = es_self * bflo(v.x);
  float a1 = es_self * bfhi(v.x);
  float a2 = es_self * bflo(v.y);
  float a3 = es_self * bfhi(v.y);

  int beg = rowptr[n], end = rowptr[n+1];
  int j = beg;
  for (; j + 3 < end; j += 4){
    int s0 = colsrc[j], s1 = colsrc[j+1], s2 = colsrc[j+2], s3 = colsrc[j+3];
    float w0 = esh[j], w1 = esh[j+1], w2 = esh[j+2], w3 = esh[j+3];
    uint2 v0 = h1q[(size_t)s0*64 + tid];
    uint2 v1 = h1q[(size_t)s1*64 + tid];
    uint2 v2 = h1q[(size_t)s2*64 + tid];
    uint2 v3 = h1q[(size_t)s3*64 + tid];
    den += (w0 + w1) + (w2 + w3);
    a0 += w0*bflo(v0.x); a1 += w0*bfhi(v0.x); a2 += w0*bflo(v0.y); a3 += w0*bfhi(v0.y);
    a0 += w1*bflo(v1.x); a1 += w1*bfhi(v1.x); a2 += w1*bflo(v1.y); a3 += w1*bfhi(v1.y);
    a0 += w2*bflo(v2.x); a1 += w2*bfhi(v2.x); a2 += w2*bflo(v2.y); a3 += w2*bfhi(v2.y);
    a0 += w3*bflo(v3.x); a1 += w3*bfhi(v3.x); a2 += w3*bflo(v3.y); a3 += w3*bfhi(v3.y);
  }
  for (; j < end; j++){
    int s0 = colsrc[j];
    float w0 = esh[j];
    uint2 v0 = h1q[(size_t)s0*64 + tid];
    den += w0;
    a0 += w0*bflo(v0.x); a1 += w0*bfhi(v0.x); a2 += w0*bflo(v0.y); a3 += w0*bfhi(v0.y);
  }

  float4 bb = ((const float4*)b1)[tid];
  float rinv = 1.f / den;
  float o0 = a0*rinv + bb.x;
  float o1 = a1*rinv + bb.y;
  float o2 = a2*rinv + bb.z;
  float o3 = a3*rinv + bb.w;
  o0 = o0 > 0.f ? o0 : (__expf(o0) - 1.f);
  o1 = o1 > 0.f ? o1 : (__expf(o1) - 1.f);
  o2 = o2 > 0.f ? o2 : (__expf(o2) - 1.f);
  o3 = o3 > 0.f ? o3 : (__expf(o3) - 1.f);
  uint2 pkd;
  pkd.x = (unsigned)bfr(o0) | ((unsigned)bfr(o1) << 16);
  pkd.y = (unsigned)bfr(o2) | ((unsigned)bfr(o3) << 16);
  ((uint2*)h1a)[(size_t)n*64 + tid] = pkd;
}

// ---- layer2 GEMM: one node per thread, W2^T staged in LDS, bf16 in, packed bf16 out ----
__global__ __launch_bounds__(256) void k_gemm2(const unsigned short* __restrict__ h1a, const float* __restrict__ W2,
    const float* __restrict__ atts2, const float* __restrict__ attd2,
    unsigned* __restrict__ h2b, float* __restrict__ a2s, float* __restrict__ a2d){
  __shared__ float W2t[HIDC*OUTC];   // [k][c] transposed, 40 KB
  __shared__ float sA[OUTC], sD[OUTC];
  int tid = threadIdx.x;
  #pragma unroll
  for (int it = 0; it < (OUTC*HIDC)/256; it++){
    int idx = it*256 + tid;
    int c = idx >> 8, k = idx & 255;
    W2t[k*OUTC + c] = W2[idx];
  }
  if (tid < OUTC){ sA[tid] = atts2[tid]; sD[tid] = attd2[tid]; }
  __syncthreads();

  int n = blockIdx.x*256 + tid;
  if (n >= NN) return;

  float acc[OUTC];
  #pragma unroll
  for (int c = 0; c < OUTC; c++) acc[c] = 0.f;

  const uint2* x2p = (const uint2*)(h1a + (size_t)n*HIDC);
  const float4* w4p = (const float4*)W2t;
  #pragma unroll 2
  for (int k4 = 0; k4 < HIDC/4; k4++){
    uint2 xu = x2p[k4];
    float xk[4] = { bflo(xu.x), bfhi(xu.x), bflo(xu.y), bfhi(xu.y) };
    #pragma unroll
    for (int kk = 0; kk < 4; kk++){
      #pragma unroll
      for (int c4 = 0; c4 < OUTC/4; c4++){
        float4 wv = w4p[(k4*4 + kk)*(OUTC/4) + c4];
        acc[c4*4+0] += xk[kk]*wv.x;
        acc[c4*4+1] += xk[kk]*wv.y;
        acc[c4*4+2] += xk[kk]*wv.z;
        acc[c4*4+3] += xk[kk]*wv.w;
      }
    }
  }

  float s2 = 0.f, d2 = 0.f;
  #pragma unroll
  for (int c = 0; c < OUTC; c++){ s2 += acc[c]*sA[c]; d2 += acc[c]*sD[c]; }

  unsigned* h2row = h2b + (size_t)n*(OUTC/2);
  #pragma unroll
  for (int c2 = 0; c2 < OUTC/2; c2++)
    h2row[c2] = (unsigned)bfr(acc[c2*2]) | ((unsigned)bfr(acc[c2*2+1]) << 16);
  a2s[n] = s2; a2d[n] = d2;
}

// ---- per-edge layer2 attention weights, CSR order ----
__global__ __launch_bounds__(256) void k_es2(const int* __restrict__ colsrc, const int* __restrict__ dstpos,
    const float* __restrict__ a2s, const float* __restrict__ a2d, float* __restrict__ es2){
  int pos = blockIdx.x*256 + threadIdx.x;
  if (pos >= NE) return;
  es2[pos] = __expf(lrelu(a2s[colsrc[pos]] + a2d[dstpos[pos]]));
}

// ---- layer2 aggregation v3: bf16 h2 rows (80B = 20 uints), 3 nodes per 64-lane wave ----
__global__ __launch_bounds__(64) void k_agg2(const unsigned* __restrict__ h2b, const float* __restrict__ a2s,
    const float* __restrict__ a2d, const float* __restrict__ es2,
    const int* __restrict__ rowptr, const int* __restrict__ colsrc,
    const float* __restrict__ b2, float* __restrict__ out){
  int tid = threadIdx.x;
  int sub = tid / 20, c2 = tid % 20;
  int n = blockIdx.x*3 + sub;
  bool valid = (sub < 3) && (n < NN);
  int nn = valid ? n : 0;

  float e = __expf(lrelu(a2s[nn] + a2d[nn]));
  float den = 1e-16f + e;
  unsigned v = h2b[(size_t)nn*20 + c2];
  float acc0 = e * bflo(v);
  float acc1 = e * bfhi(v);

  int beg = valid ? rowptr[nn] : 0;
  int end = valid ? rowptr[nn+1] : 0;
  int j = beg;
  for (; j + 3 < end; j += 4){
    int s0 = colsrc[j], s1 = colsrc[j+1], s2 = colsrc[j+2], s3 = colsrc[j+3];
    float w0 = es2[j], w1 = es2[j+1], w2 = es2[j+2], w3 = es2[j+3];
    unsigned g0 = h2b[(size_t)s0*20 + c2];
    unsigned g1 = h2b[(size_t)s1*20 + c2];
    unsigned g2 = h2b[(size_t)s2*20 + c2];
    unsigned g3 = h2b[(size_t)s3*20 + c2];
    den += (w0 + w1) + (w2 + w3);
    acc0 += w0*bflo(g0) + w1*bflo(g1);
    acc1 += w0*bfhi(g0) + w1*bfhi(g1);
    acc0 += w2*bflo(g2) + w3*bflo(g3);
    acc1 += w2*bfhi(g2) + w3*bfhi(g3);
  }
  for (; j < end; j++){
    int s0 = colsrc[j];
    float w0 = es2[j];
    unsigned g0 = h2b[(size_t)s0*20 + c2];
    den += w0;
    acc0 += w0*bflo(g0);
    acc1 += w0*bfhi(g0);
  }

  if (valid){
    float rinv = 1.f / den;
    float2 o;
    o.x = acc0*rinv + b2[c2*2];
    o.y = acc1*rinv + b2[c2*2+1];
    ((float2*)(out + (size_t)n*OUTC))[c2] = o;
  }
}

extern "C" void kernel_launch(void* const* d_in, const int* in_sizes, int n_in,
                              void* d_out, int out_size, void* d_ws, size_t ws_size,
                              hipStream_t stream){
  const float* x    = (const float*)d_in[0];
  const void*  ei   = d_in[1];
  const float* W1   = (const float*)d_in[2];
  const float* as1w = (const float*)d_in[3];
  const float* ad1w = (const float*)d_in[4];
  const float* b1   = (const float*)d_in[5];
  const float* W2   = (const float*)d_in[6];
  const float* as2w = (const float*)d_in[7];
  const float* ad2w = (const float*)d_in[8];
  const float* b2   = (const float*)d_in[9];
  float* out = (float*)d_out;

  char* base = (char*)d_ws;
  size_t off = 0;
  auto alloc = [&](size_t bytes)->char*{ char* r = base + off; off += (bytes + 255) & ~(size_t)255; return r; };
  int* flag   = (int*)alloc(sizeof(int));
  int* src32  = (int*)alloc((size_t)NE*sizeof(int));
  int* dst32  = (int*)alloc((size_t)NE*sizeof(int));
  int* deg    = (int*)alloc((size_t)NN*sizeof(int));
  int* rowptr = (int*)alloc((size_t)(NN+1)*sizeof(int));
  int* fillc  = (int*)alloc((size_t)NN*sizeof(int));
  int* sums   = (int*)alloc(64*sizeof(int));
  int* colsrc = (int*)alloc((size_t)NE*sizeof(int));
  int* dstpos = (int*)alloc((size_t)NE*sizeof(int));
  float* esp  = (float*)alloc((size_t)NE*NH*sizeof(float));
  float* es2  = (float*)alloc((size_t)NE*sizeof(float));
  unsigned short* w1b = (unsigned short*)alloc((size_t)HIDC*INC*sizeof(unsigned short));
  unsigned short* h1b = (unsigned short*)alloc((size_t)NN*HIDC*sizeof(unsigned short));
  unsigned short* h1a = (unsigned short*)alloc((size_t)NN*HIDC*sizeof(unsigned short));
  float* as1  = (float*)alloc((size_t)NN*NH*sizeof(float));
  float* ad1  = (float*)alloc((size_t)NN*NH*sizeof(float));
  unsigned* h2b = (unsigned*)alloc((size_t)NN*(OUTC/2)*sizeof(unsigned));
  float* a2s  = (float*)alloc((size_t)NN*sizeof(float));
  float* a2d  = (float*)alloc((size_t)NN*sizeof(float));

  hipMemsetAsync(deg,   0, (size_t)NN*sizeof(int), stream);
  hipMemsetAsync(fillc, 0, (size_t)NN*sizeof(int), stream);

  int gE = (NE + 255)/256;
  int nchunks = (NN + 1023)/1024;
  k_detect<<<1, 64, 0, stream>>>((const long long*)ei, flag);
  k_convert<<<gE, 256, 0, stream>>>(ei, flag, src32, dst32, deg);
  k_scan1<<<nchunks, 1024, 0, stream>>>(deg, rowptr, sums);
  k_scan2<<<1, 64, 0, stream>>>(sums, nchunks);
  k_scan3<<<(NN + 255)/256, 256, 0, stream>>>(rowptr, sums);
  k_fill<<<gE, 256, 0, stream>>>(src32, dst32, rowptr, fillc, colsrc, dstpos);
  k_cvt<<<(HIDC*INC/4 + 255)/256, 256, 0, stream>>>(W1, w1b, HIDC*INC/4);
  k_gemm1<<<(NN + 63)/64, 256, 0, stream>>>(x, w1b, as1w, ad1w, h1b, as1, ad1);
  k_es<<<gE, 256, 0, stream>>>(colsrc, dstpos, as1, ad1, esp);
  k_agg1<<<NN, 64, 0, stream>>>(h1b, esp, as1, ad1, rowptr, colsrc, b1, h1a);
  k_gemm2<<<(NN + 255)/256, 256, 0, stream>>>(h1a, W2, as2w, ad2w, h2b, a2s, a2d);
  k_es2<<<gE, 256, 0, stream>>>(colsrc, dstpos, a2s, a2d, es2);
  k_agg2<<<(NN + 2)/3, 64, 0, stream>>>(h2b, a2s, a2d, es2, rowptr, colsrc, b2, out);
}

// Round 10
// 283.699 us; speedup vs baseline: 1.2823x; 1.0666x over previous
//
#include <hip/hip_runtime.h>
#include <hip/hip_bf16.h>
#include <cstdint>
#include <cstddef>

#define NN 50000
#define NE 800000
#define INC 128
#define HIDC 256
#define NH 4
#define OUTC 40

typedef __attribute__((ext_vector_type(8))) short short8_t;
typedef __attribute__((ext_vector_type(4))) float f32x4_t;

__device__ __forceinline__ float lrelu(float x){ return x > 0.f ? x : 0.2f*x; }
__device__ __forceinline__ unsigned short bfr(float f){
  __hip_bfloat16 h = __float2bfloat16(f);
  return *reinterpret_cast<unsigned short*>(&h);
}
__device__ __forceinline__ float bflo(unsigned u){ return __uint_as_float(u << 16); }
__device__ __forceinline__ float bfhi(unsigned u){ return __uint_as_float(u & 0xffff0000u); }

// ---- edge dtype detection: int64 view of int32 pairs gives values >= 2^32 ----
__global__ __launch_bounds__(64) void k_detect(const long long* __restrict__ ei, int* __restrict__ flag){
  int t = threadIdx.x;
  long long v = ei[(long long)t * (NE/64)];
  bool ok = (v >= 0) && (v < NN);
  unsigned long long m = __ballot(ok);
  if (t == 0) *flag = (m == 0xFFFFFFFFFFFFFFFFull) ? 1 : 0;
}

// ---- convert + degree count fused ----
__global__ __launch_bounds__(256) void k_convert(const void* __restrict__ ei, const int* __restrict__ flag,
                                                 int* __restrict__ src32, int* __restrict__ dst32,
                                                 int* __restrict__ deg){
  int e = blockIdx.x*256 + threadIdx.x;
  if (e >= NE) return;
  int s, d;
  if (*flag){
    const long long* p = (const long long*)ei;
    s = (int)p[e]; d = (int)p[NE+e];
  } else {
    const int* p = (const int*)ei;
    s = p[e]; d = p[NE+e];
  }
  s = min(max(s,0),NN-1); d = min(max(d,0),NN-1);
  src32[e] = s; dst32[e] = d;
  atomicAdd(&deg[d], 1);
}

// ---- exclusive scan of deg -> rowptr (3-kernel, chunk=1024) ----
__global__ __launch_bounds__(1024) void k_scan1(const int* __restrict__ deg, int* __restrict__ rowptr, int* __restrict__ sums){
  __shared__ int sh[1024];
  int t = threadIdx.x; int i = blockIdx.x*1024 + t;
  sh[t] = (i < NN) ? deg[i] : 0;
  __syncthreads();
  for (int off = 1; off < 1024; off <<= 1){
    int add = (t >= off) ? sh[t-off] : 0;
    __syncthreads();
    sh[t] += add;
    __syncthreads();
  }
  if (i < NN) rowptr[i+1] = sh[t];
  if (t == 1023) sums[blockIdx.x] = sh[1023];
}

__global__ void k_scan2(int* sums, int nchunks){
  if (threadIdx.x == 0 && blockIdx.x == 0){
    int acc = 0;
    for (int i = 0; i < nchunks; i++){ int v = sums[i]; sums[i] = acc; acc += v; }
  }
}

__global__ __launch_bounds__(256) void k_scan3(int* __restrict__ rowptr, const int* __restrict__ sums){
  int i = blockIdx.x*256 + threadIdx.x;
  if (i < NN) rowptr[i+1] += sums[i >> 10];
  if (i == 0) rowptr[0] = 0;
}

// ---- CSR fill: single packed int2 scatter (src, dst) per edge ----
__global__ __launch_bounds__(256) void k_fill(const int* __restrict__ src32, const int* __restrict__ dst32,
                                              const int* __restrict__ rowptr, int* __restrict__ fill,
                                              int2* __restrict__ edge2){
  int e = blockIdx.x*256 + threadIdx.x;
  if (e >= NE) return;
  int d = dst32[e];
  int pos = rowptr[d] + atomicAdd(&fill[d], 1);
  edge2[pos] = make_int2(src32[e], d);
}

// ---- fp32 -> bf16 conversion (used for W1) ----
__global__ __launch_bounds__(256) void k_cvt(const float* __restrict__ in, unsigned short* __restrict__ out, int n4){
  int i = blockIdx.x*256 + threadIdx.x;
  if (i >= n4) return;
  float4 v = ((const float4*)in)[i];
  ushort4 o;
  o.x = bfr(v.x); o.y = bfr(v.y); o.z = bfr(v.z); o.w = bfr(v.w);
  ((ushort4*)out)[i] = o;
}

// ---- layer1 GEMM: MFMA bf16, wave = 16 rows x 256 cols, fused attention dots ----
__global__ __launch_bounds__(256) void k_gemm1(const float* __restrict__ x, const unsigned short* __restrict__ w1b,
    const float* __restrict__ atts, const float* __restrict__ attd,
    unsigned short* __restrict__ h1b, float* __restrict__ as1, float* __restrict__ ad1){
  int tid = threadIdx.x;
  int wv = tid >> 6, l = tid & 63;
  int m0 = blockIdx.x*64 + wv*16;
  int lr = l & 15;
  int lk = l >> 4;

  short8_t a[4];
  int arow = m0 + lr; if (arow > NN-1) arow = NN-1;
  const float* xrow = x + (size_t)arow*INC + lk*8;
  #pragma unroll
  for (int kt = 0; kt < 4; kt++){
    float4 f0 = *(const float4*)(xrow + kt*32);
    float4 f1 = *(const float4*)(xrow + kt*32 + 4);
    short8_t av;
    av[0] = (short)bfr(f0.x); av[1] = (short)bfr(f0.y);
    av[2] = (short)bfr(f0.z); av[3] = (short)bfr(f0.w);
    av[4] = (short)bfr(f1.x); av[5] = (short)bfr(f1.y);
    av[6] = (short)bfr(f1.z); av[7] = (short)bfr(f1.w);
    a[kt] = av;
  }

  const unsigned short* bbase = w1b + (size_t)lr*INC + lk*8;

  for (int h = 0; h < NH; h++){
    float ps[4] = {0.f,0.f,0.f,0.f};
    float pd[4] = {0.f,0.f,0.f,0.f};
    #pragma unroll
    for (int t = 0; t < 4; t++){
      int nt = h*4 + t;
      f32x4_t acc = {0.f,0.f,0.f,0.f};
      #pragma unroll
      for (int kt = 0; kt < 4; kt++){
        short8_t bv = *(const short8_t*)(bbase + (size_t)nt*16*INC + kt*32);
        acc = __builtin_amdgcn_mfma_f32_16x16x32_bf16(a[kt], bv, acc, 0, 0, 0);
      }
      float sa = atts[nt*16 + lr], sd = attd[nt*16 + lr];
      #pragma unroll
      for (int r = 0; r < 4; r++){
        float v = acc[r];
        ps[r] += v*sa; pd[r] += v*sd;
        int node = m0 + lk*4 + r;
        if (node < NN) h1b[(size_t)node*HIDC + nt*16 + lr] = bfr(v);
      }
    }
    #pragma unroll
    for (int r = 0; r < 4; r++){
      float p = ps[r], q = pd[r];
      p += __shfl_xor(p, 1); p += __shfl_xor(p, 2); p += __shfl_xor(p, 4); p += __shfl_xor(p, 8);
      q += __shfl_xor(q, 1); q += __shfl_xor(q, 2); q += __shfl_xor(q, 4); q += __shfl_xor(q, 8);
      int node = m0 + lk*4 + r;
      if (lr == 0 && node < NN){ as1[node*NH + h] = p; ad1[node*NH + h] = q; }
    }
  }
}

// ---- per-edge attention weights, CSR order: coalesced edge2 reads, coalesced planar writes ----
__global__ __launch_bounds__(256) void k_es(const int2* __restrict__ edge2,
    const float* __restrict__ as1, const float* __restrict__ ad1, float* __restrict__ esp){
  int pos = blockIdx.x*256 + threadIdx.x;
  if (pos >= NE) return;
  int2 sd = edge2[pos];
  float4 vs = ((const float4*)as1)[sd.x];
  float4 vd = ((const float4*)ad1)[sd.y];
  esp[0*NE + pos] = __expf(lrelu(vs.x + vd.x));
  esp[1*NE + pos] = __expf(lrelu(vs.y + vd.y));
  esp[2*NE + pos] = __expf(lrelu(vs.z + vd.z));
  esp[3*NE + pos] = __expf(lrelu(vs.w + vd.w));
}

// ---- layer1 aggregation: 1 wave/node, 4 ch/thread, planar es, unroll-8 MLP, bf16 out ----
__global__ __launch_bounds__(64) void k_agg1(const unsigned short* __restrict__ h1b,
    const float* __restrict__ esp, const float* __restrict__ as1, const float* __restrict__ ad1,
    const int2* __restrict__ edge2, const int* __restrict__ rowptr,
    const float* __restrict__ b1, unsigned short* __restrict__ h1a){
  int n = blockIdx.x; int tid = threadIdx.x; int head = tid >> 4;
  const uint2* h1q = (const uint2*)h1b;          // row = 64 uint2
  const float* esh = esp + (size_t)head*NE;

  float es_self = __expf(lrelu(as1[n*NH + head] + ad1[n*NH + head]));
  float den = 1e-16f + es_self;
  uint2 v = h1q[(size_t)n*64 + tid];
  float a0 = es_self * bflo(v.x);
  float a1 = es_self * bfhi(v.x);
  float a2 = es_self * bflo(v.y);
  float a3 = es_self * bfhi(v.y);

  int beg = rowptr[n], end = rowptr[n+1];
  int j = beg;
  for (; j + 7 < end; j += 8){
    int s[8]; float w[8]; uint2 g[8];
    #pragma unroll
    for (int u = 0; u < 8; u++){ s[u] = edge2[j+u].x; w[u] = esh[j+u]; }
    #pragma unroll
    for (int u = 0; u < 8; u++) g[u] = h1q[(size_t)s[u]*64 + tid];
    #pragma unroll
    for (int u = 0; u < 8; u++){
      den += w[u];
      a0 += w[u]*bflo(g[u].x); a1 += w[u]*bfhi(g[u].x);
      a2 += w[u]*bflo(g[u].y); a3 += w[u]*bfhi(g[u].y);
    }
  }
  for (; j + 3 < end; j += 4){
    int s[4]; float w[4]; uint2 g[4];
    #pragma unroll
    for (int u = 0; u < 4; u++){ s[u] = edge2[j+u].x; w[u] = esh[j+u]; }
    #pragma unroll
    for (int u = 0; u < 4; u++) g[u] = h1q[(size_t)s[u]*64 + tid];
    #pragma unroll
    for (int u = 0; u < 4; u++){
      den += w[u];
      a0 += w[u]*bflo(g[u].x); a1 += w[u]*bfhi(g[u].x);
      a2 += w[u]*bflo(g[u].y); a3 += w[u]*bfhi(g[u].y);
    }
  }
  for (; j < end; j++){
    int s0 = edge2[j].x;
    float w0 = esh[j];
    uint2 g0 = h1q[(size_t)s0*64 + tid];
    den += w0;
    a0 += w0*bflo(g0.x); a1 += w0*bfhi(g0.x); a2 += w0*bflo(g0.y); a3 += w0*bfhi(g0.y);
  }

  float4 bb = ((const float4*)b1)[tid];
  float rinv = 1.f / den;
  float o0 = a0*rinv + bb.x;
  float o1 = a1*rinv + bb.y;
  float o2 = a2*rinv + bb.z;
  float o3 = a3*rinv + bb.w;
  o0 = o0 > 0.f ? o0 : (__expf(o0) - 1.f);
  o1 = o1 > 0.f ? o1 : (__expf(o1) - 1.f);
  o2 = o2 > 0.f ? o2 : (__expf(o2) - 1.f);
  o3 = o3 > 0.f ? o3 : (__expf(o3) - 1.f);
  uint2 pkd;
  pkd.x = (unsigned)bfr(o0) | ((unsigned)bfr(o1) << 16);
  pkd.y = (unsigned)bfr(o2) | ((unsigned)bfr(o3) << 16);
  ((uint2*)h1a)[(size_t)n*64 + tid] = pkd;
}

// ---- layer2 GEMM: one node per thread, 128-thread blocks (grid ~391 > 256 CUs),
//      W2^T staged in LDS, bf16 in, packed bf16 out ----
__global__ __launch_bounds__(128) void k_gemm2(const unsigned short* __restrict__ h1a, const float* __restrict__ W2,
    const float* __restrict__ atts2, const float* __restrict__ attd2,
    unsigned* __restrict__ h2b, float* __restrict__ a2s, float* __restrict__ a2d){
  __shared__ float W2t[HIDC*OUTC];   // [k][c] transposed, 40 KB
  __shared__ float sA[OUTC], sD[OUTC];
  int tid = threadIdx.x;
  #pragma unroll
  for (int it = 0; it < (OUTC*HIDC)/128; it++){
    int idx = it*128 + tid;
    int c = idx >> 8, k = idx & 255;
    W2t[k*OUTC + c] = W2[idx];
  }
  if (tid < OUTC){ sA[tid] = atts2[tid]; sD[tid] = attd2[tid]; }
  __syncthreads();

  int n = blockIdx.x*128 + tid;
  if (n >= NN) return;

  float acc[OUTC];
  #pragma unroll
  for (int c = 0; c < OUTC; c++) acc[c] = 0.f;

  const uint2* x2p = (const uint2*)(h1a + (size_t)n*HIDC);
  const float4* w4p = (const float4*)W2t;
  #pragma unroll 2
  for (int k4 = 0; k4 < HIDC/4; k4++){
    uint2 xu = x2p[k4];
    float xk[4] = { bflo(xu.x), bfhi(xu.x), bflo(xu.y), bfhi(xu.y) };
    #pragma unroll
    for (int kk = 0; kk < 4; kk++){
      #pragma unroll
      for (int c4 = 0; c4 < OUTC/4; c4++){
        float4 wv = w4p[(k4*4 + kk)*(OUTC/4) + c4];
        acc[c4*4+0] += xk[kk]*wv.x;
        acc[c4*4+1] += xk[kk]*wv.y;
        acc[c4*4+2] += xk[kk]*wv.z;
        acc[c4*4+3] += xk[kk]*wv.w;
      }
    }
  }

  float s2 = 0.f, d2 = 0.f;
  #pragma unroll
  for (int c = 0; c < OUTC; c++){ s2 += acc[c]*sA[c]; d2 += acc[c]*sD[c]; }

  unsigned* h2row = h2b + (size_t)n*(OUTC/2);
  #pragma unroll
  for (int c2 = 0; c2 < OUTC/2; c2++)
    h2row[c2] = (unsigned)bfr(acc[c2*2]) | ((unsigned)bfr(acc[c2*2+1]) << 16);
  a2s[n] = s2; a2d[n] = d2;
}

// ---- per-edge layer2 attention weights, CSR order ----
__global__ __launch_bounds__(256) void k_es2(const int2* __restrict__ edge2,
    const float* __restrict__ a2s, const float* __restrict__ a2d, float* __restrict__ es2){
  int pos = blockIdx.x*256 + threadIdx.x;
  if (pos >= NE) return;
  int2 sd = edge2[pos];
  es2[pos] = __expf(lrelu(a2s[sd.x] + a2d[sd.y]));
}

// ---- layer2 aggregation: bf16 h2 rows (80B = 20 uints), 3 nodes per 64-lane wave ----
__global__ __launch_bounds__(64) void k_agg2(const unsigned* __restrict__ h2b, const float* __restrict__ a2s,
    const float* __restrict__ a2d, const float* __restrict__ es2,
    const int2* __restrict__ edge2, const int* __restrict__ rowptr,
    const float* __restrict__ b2, float* __restrict__ out){
  int tid = threadIdx.x;
  int sub = tid / 20, c2 = tid % 20;
  int n = blockIdx.x*3 + sub;
  bool valid = (sub < 3) && (n < NN);
  int nn = valid ? n : 0;

  float e = __expf(lrelu(a2s[nn] + a2d[nn]));
  float den = 1e-16f + e;
  unsigned v = h2b[(size_t)nn*20 + c2];
  float acc0 = e * bflo(v);
  float acc1 = e * bfhi(v);

  int beg = valid ? rowptr[nn] : 0;
  int end = valid ? rowptr[nn+1] : 0;
  int j = beg;
  for (; j + 3 < end; j += 4){
    int s0 = edge2[j].x, s1 = edge2[j+1].x, s2 = edge2[j+2].x, s3 = edge2[j+3].x;
    float w0 = es2[j], w1 = es2[j+1], w2 = es2[j+2], w3 = es2[j+3];
    unsigned g0 = h2b[(size_t)s0*20 + c2];
    unsigned g1 = h2b[(size_t)s1*20 + c2];
    unsigned g2 = h2b[(size_t)s2*20 + c2];
    unsigned g3 = h2b[(size_t)s3*20 + c2];
    den += (w0 + w1) + (w2 + w3);
    acc0 += w0*bflo(g0) + w1*bflo(g1);
    acc1 += w0*bfhi(g0) + w1*bfhi(g1);
    acc0 += w2*bflo(g2) + w3*bflo(g3);
    acc1 += w2*bfhi(g2) + w3*bfhi(g3);
  }
  for (; j < end; j++){
    int s0 = edge2[j].x;
    float w0 = es2[j];
    unsigned g0 = h2b[(size_t)s0*20 + c2];
    den += w0;
    acc0 += w0*bflo(g0);
    acc1 += w0*bfhi(g0);
  }

  if (valid){
    float rinv = 1.f / den;
    float2 o;
    o.x = acc0*rinv + b2[c2*2];
    o.y = acc1*rinv + b2[c2*2+1];
    ((float2*)(out + (size_t)n*OUTC))[c2] = o;
  }
}

extern "C" void kernel_launch(void* const* d_in, const int* in_sizes, int n_in,
                              void* d_out, int out_size, void* d_ws, size_t ws_size,
                              hipStream_t stream){
  const float* x    = (const float*)d_in[0];
  const void*  ei   = d_in[1];
  const float* W1   = (const float*)d_in[2];
  const float* as1w = (const float*)d_in[3];
  const float* ad1w = (const float*)d_in[4];
  const float* b1   = (const float*)d_in[5];
  const float* W2   = (const float*)d_in[6];
  const float* as2w = (const float*)d_in[7];
  const float* ad2w = (const float*)d_in[8];
  const float* b2   = (const float*)d_in[9];
  float* out = (float*)d_out;

  char* base = (char*)d_ws;
  size_t off = 0;
  auto alloc = [&](size_t bytes)->char*{ char* r = base + off; off += (bytes + 255) & ~(size_t)255; return r; };
  int* flag   = (int*)alloc(sizeof(int));
  int* src32  = (int*)alloc((size_t)NE*sizeof(int));
  int* dst32  = (int*)alloc((size_t)NE*sizeof(int));
  int* deg    = (int*)alloc((size_t)NN*sizeof(int));
  int* rowptr = (int*)alloc((size_t)(NN+1)*sizeof(int));
  int* fillc  = (int*)alloc((size_t)NN*sizeof(int));
  int* sums   = (int*)alloc(64*sizeof(int));
  int2* edge2 = (int2*)alloc((size_t)NE*sizeof(int2));
  float* esp  = (float*)alloc((size_t)NE*NH*sizeof(float));
  float* es2  = (float*)alloc((size_t)NE*sizeof(float));
  unsigned short* w1b = (unsigned short*)alloc((size_t)HIDC*INC*sizeof(unsigned short));
  unsigned short* h1b = (unsigned short*)alloc((size_t)NN*HIDC*sizeof(unsigned short));
  unsigned short* h1a = (unsigned short*)alloc((size_t)NN*HIDC*sizeof(unsigned short));
  float* as1  = (float*)alloc((size_t)NN*NH*sizeof(float));
  float* ad1  = (float*)alloc((size_t)NN*NH*sizeof(float));
  unsigned* h2b = (unsigned*)alloc((size_t)NN*(OUTC/2)*sizeof(unsigned));
  float* a2s  = (float*)alloc((size_t)NN*sizeof(float));
  float* a2d  = (float*)alloc((size_t)NN*sizeof(float));

  hipMemsetAsync(deg,   0, (size_t)NN*sizeof(int), stream);
  hipMemsetAsync(fillc, 0, (size_t)NN*sizeof(int), stream);

  int gE = (NE + 255)/256;
  int nchunks = (NN + 1023)/1024;
  k_detect<<<1, 64, 0, stream>>>((const long long*)ei, flag);
  k_convert<<<gE, 256, 0, stream>>>(ei, flag, src32, dst32, deg);
  k_scan1<<<nchunks, 1024, 0, stream>>>(deg, rowptr, sums);
  k_scan2<<<1, 64, 0, stream>>>(sums, nchunks);
  k_scan3<<<(NN + 255)/256, 256, 0, stream>>>(rowptr, sums);
  k_fill<<<gE, 256, 0, stream>>>(src32, dst32, rowptr, fillc, edge2);
  k_cvt<<<(HIDC*INC/4 + 255)/256, 256, 0, stream>>>(W1, w1b, HIDC*INC/4);
  k_gemm1<<<(NN + 63)/64, 256, 0, stream>>>(x, w1b, as1w, ad1w, h1b, as1, ad1);
  k_es<<<gE, 256, 0, stream>>>(edge2, as1, ad1, esp);
  k_agg1<<<NN, 64, 0, stream>>>(h1b, esp, as1, ad1, edge2, rowptr, b1, h1a);
  k_gemm2<<<(NN + 127)/128, 128, 0, stream>>>(h1a, W2, as2w, ad2w, h2b, a2s, a2d);
  k_es2<<<gE, 256, 0, stream>>>(edge2, a2s, a2d, es2);
  k_agg2<<<(NN + 2)/3, 64, 0, stream>>>(h2b, a2s, a2d, es2, edge2, rowptr, b2, out);
}